// Round 1
// baseline (1073.356 us; speedup 1.0000x reference)
//
#include <hip/hip_runtime.h>

#define T_STEPS 2048
#define BATCH 16
#define DIM 1024
#define NDIM 64
#define M_TOTAL (T_STEPS * BATCH)  // 32768

typedef __attribute__((ext_vector_type(8))) short bf16x8;
typedef __attribute__((ext_vector_type(4))) float f32x4;

__device__ inline unsigned short f2bf(float f) {
    unsigned u = __float_as_uint(f);
    return (unsigned short)((u + 0x7FFFu + ((u >> 16) & 1u)) >> 16);
}

// C[m][n] = sum_k x[m][k] * W[n][k]  (both K-contiguous; m97 gemm_bt pattern)
// block: 128 M-rows x 64 N-cols, one W matrix per blockIdx.y
__global__ __launch_bounds__(256) void proj_kernel(
    const float* __restrict__ x,
    const float* __restrict__ Wk, const float* __restrict__ Wv,
    const float* __restrict__ Wq, const float* __restrict__ Wa,
    float* __restrict__ outBase) {
    const int BK = 32;
    const int LDA = 40;  // bf16 elems per row (+8 pad -> 80B stride, conflict-friendly)
    __shared__ unsigned short lA[128 * 40];
    __shared__ unsigned short lB[64 * 40];

    int which = blockIdx.y;
    const float* W = (which == 0) ? Wk : (which == 1) ? Wv : (which == 2) ? Wq : Wa;
    float* outW = outBase + (size_t)which * M_TOTAL * NDIM;

    int m0 = blockIdx.x * 128;
    int tid = threadIdx.x;
    int wave = tid >> 6;
    int lane = tid & 63;
    int lrow = lane & 15;
    int quad = lane >> 4;

    f32x4 acc[2][4];
#pragma unroll
    for (int a = 0; a < 2; a++)
#pragma unroll
        for (int b = 0; b < 4; b++) acc[a][b] = (f32x4)(0.f);

    // staging assignment
    int arow = tid >> 1;          // 0..127
    int acol = (tid & 1) * 16;    // 0 or 16 (16 floats via 4x float4)
    int brow = tid >> 2;          // 0..63
    int bcol = (tid & 3) * 8;     // 8 floats via 2x float4

    for (int k0 = 0; k0 < DIM; k0 += BK) {
        const float4* pa = (const float4*)(x + (size_t)(m0 + arow) * DIM + k0 + acol);
        float4 a0 = pa[0], a1 = pa[1], a2 = pa[2], a3 = pa[3];
        const float4* pb = (const float4*)(W + (size_t)brow * DIM + k0 + bcol);
        float4 b0 = pb[0], b1 = pb[1];

        __syncthreads();  // protect previous iteration's frag reads

        {
            ushort4 p;
            p.x = f2bf(a0.x); p.y = f2bf(a0.y); p.z = f2bf(a0.z); p.w = f2bf(a0.w);
            *(ushort4*)&lA[arow * LDA + acol + 0] = p;
            p.x = f2bf(a1.x); p.y = f2bf(a1.y); p.z = f2bf(a1.z); p.w = f2bf(a1.w);
            *(ushort4*)&lA[arow * LDA + acol + 4] = p;
            p.x = f2bf(a2.x); p.y = f2bf(a2.y); p.z = f2bf(a2.z); p.w = f2bf(a2.w);
            *(ushort4*)&lA[arow * LDA + acol + 8] = p;
            p.x = f2bf(a3.x); p.y = f2bf(a3.y); p.z = f2bf(a3.z); p.w = f2bf(a3.w);
            *(ushort4*)&lA[arow * LDA + acol + 12] = p;
            p.x = f2bf(b0.x); p.y = f2bf(b0.y); p.z = f2bf(b0.z); p.w = f2bf(b0.w);
            *(ushort4*)&lB[brow * LDA + bcol + 0] = p;
            p.x = f2bf(b1.x); p.y = f2bf(b1.y); p.z = f2bf(b1.z); p.w = f2bf(b1.w);
            *(ushort4*)&lB[brow * LDA + bcol + 4] = p;
        }
        __syncthreads();

        bf16x8 af[2], bfr[4];
#pragma unroll
        for (int rt = 0; rt < 2; rt++)
            af[rt] = *(const bf16x8*)&lA[(wave * 32 + rt * 16 + lrow) * LDA + quad * 8];
#pragma unroll
        for (int bt = 0; bt < 4; bt++)
            bfr[bt] = *(const bf16x8*)&lB[(bt * 16 + lrow) * LDA + quad * 8];
#pragma unroll
        for (int rt = 0; rt < 2; rt++)
#pragma unroll
            for (int bt = 0; bt < 4; bt++)
                acc[rt][bt] = __builtin_amdgcn_mfma_f32_16x16x32_bf16(
                    af[rt], bfr[bt], acc[rt][bt], 0, 0, 0);
    }

    // epilogue: C/D layout col = lane&15, row = quad*4 + reg  [m89-verified]
#pragma unroll
    for (int rt = 0; rt < 2; rt++)
#pragma unroll
        for (int bt = 0; bt < 4; bt++)
#pragma unroll
            for (int reg = 0; reg < 4; reg++) {
                int m = m0 + wave * 32 + rt * 16 + quad * 4 + reg;
                int n = bt * 16 + lrow;
                outW[(size_t)m * NDIM + n] = acc[rt][bt][reg];
            }
}

// Recurrence: 16 batches x 16 row-groups blocks; 64 threads; 16 lanes/row, 4 cols/lane.
__global__ __launch_bounds__(64) void recur_kernel(
    const float* __restrict__ Kp, const float* __restrict__ Vp,
    const float* __restrict__ Qp, const float* __restrict__ Ap,
    const float* __restrict__ S0, const float* __restrict__ d_alpha,
    const float* __restrict__ b_alpha, float* __restrict__ out,
    float* __restrict__ Sout) {
    int b = blockIdx.y;
    int g = blockIdx.x;
    int lane = threadIdx.x;
    int r = lane >> 4;     // row within group
    int c = lane & 15;     // column group
    int i = g * 4 + r;     // state row 0..63

    float4 s = *(const float4*)(S0 + ((size_t)b * NDIM + i) * NDIM + c * 4);
    float da = d_alpha[i];
    float ba = b_alpha[i];

    // prefetch t=0
    size_t base0 = (size_t)b * NDIM;
    float4 k4 = *(const float4*)(Kp + base0 + c * 4);
    float4 q4 = *(const float4*)(Qp + base0 + c * 4);
    float vi = Vp[base0 + i];
    float ai = Ap[base0 + i];

    for (int t = 0; t < T_STEPS; ++t) {
        float4 ck = k4, cq = q4;
        float cv = vi, ca = ai;

        // prefetch next step (clamped; off critical path)
        int tn = (t + 1 < T_STEPS) ? (t + 1) : t;
        size_t nb = ((size_t)tn * BATCH + b) * NDIM;
        k4 = *(const float4*)(Kp + nb + c * 4);
        q4 = *(const float4*)(Qp + nb + c * 4);
        vi = Vp[nb + i];
        ai = Ap[nb + i];

        float rk = ck.x * s.x + ck.y * s.y + ck.z * s.z + ck.w * s.w;
        float rq = cq.x * s.x + cq.y * s.y + cq.z * s.z + cq.w * s.w;
        float kq = ck.x * cq.x + ck.y * cq.y + ck.z * cq.z + ck.w * cq.w;
#pragma unroll
        for (int m = 1; m < 16; m <<= 1) {
            rk += __shfl_xor(rk, m, 64);
            rq += __shfl_xor(rq, m, 64);
            kq += __shfl_xor(kq, m, 64);
        }

        float z = ca + da * rk + ba;
        float alpha = __builtin_amdgcn_rcpf(1.f + __expf(-z));
        float u = (1.f - alpha) * cv;

        s.x = alpha * s.x + u * ck.x;
        s.y = alpha * s.y + u * ck.y;
        s.z = alpha * s.z + u * ck.z;
        s.w = alpha * s.w + u * ck.w;

        // out = S_new . q = alpha*(S_old.q) + u*(k.q)   (exact)
        float o = alpha * rq + u * kq;
        float sg = __builtin_amdgcn_rcpf(1.f + __expf(-o));
        if (c == 0) out[((size_t)t * BATCH + b) * NDIM + i] = o * o * sg;
    }

    *(float4*)(Sout + ((size_t)b * NDIM + i) * NDIM + c * 4) = s;
}

extern "C" void kernel_launch(void* const* d_in, const int* in_sizes, int n_in,
                              void* d_out, int out_size, void* d_ws, size_t ws_size,
                              hipStream_t stream) {
    const float* x  = (const float*)d_in[0];
    const float* S0 = (const float*)d_in[1];
    const float* Wk = (const float*)d_in[2];
    const float* Wv = (const float*)d_in[3];
    const float* Wq = (const float*)d_in[4];
    const float* Wa = (const float*)d_in[5];
    const float* da = (const float*)d_in[6];
    const float* ba = (const float*)d_in[7];

    float* out = (float*)d_out;
    float* Sout = out + (size_t)T_STEPS * BATCH * NDIM;

    float* proj = (float*)d_ws;  // needs 4 * 32768 * 64 * 4B = 33.6 MB
    const size_t per = (size_t)M_TOTAL * NDIM;
    float* Kp = proj;
    float* Vp = proj + per;
    float* Qp = proj + 2 * per;
    float* Ap = proj + 3 * per;

    proj_kernel<<<dim3(M_TOTAL / 128, 4), dim3(256), 0, stream>>>(x, Wk, Wv, Wq, Wa, proj);
    recur_kernel<<<dim3(16, BATCH), dim3(64), 0, stream>>>(Kp, Vp, Qp, Ap, S0, da, ba, out, Sout);
}

// Round 2
// 678.137 us; speedup vs baseline: 1.5828x; 1.5828x over previous
//
#include <hip/hip_runtime.h>
#include <hip/hip_bf16.h>

#define T_STEPS 2048
#define BATCH 16
#define DIM 1024
#define NDIM 64
#define M_TOTAL (T_STEPS * BATCH)  // 32768
#define PD 8                       // recurrence prefetch depth

typedef __attribute__((ext_vector_type(8))) short bf16x8;
typedef __attribute__((ext_vector_type(4))) float f32x4;

__device__ inline unsigned pk_bf(float lo, float hi) {
    __hip_bfloat162 h = __float22bfloat162_rn(float2{lo, hi});
    return *(unsigned*)&h;  // v_cvt_pk_bf16_f32 on gfx950
}

// ---------------- fused projection: C[m][n] = x[m][:] . W(n)[:] ----------------
// One pass over x (read once), N=256 = 4 matrices x 64. m97-style MFMA tile.
__global__ __launch_bounds__(256, 1) void proj_kernel(
    const float* __restrict__ x,
    const float* __restrict__ Wk, const float* __restrict__ Wv,
    const float* __restrict__ Wq, const float* __restrict__ Wa,
    float* __restrict__ outBase) {
    const int LDA = 40;  // shorts per row (+8 pad)
    __shared__ unsigned short lA[128 * 40];  // 10 KB
    __shared__ unsigned short lB[256 * 40];  // 20 KB

    int m0 = blockIdx.x * 128;
    int tid = threadIdx.x;
    int wave = tid >> 6;
    int lane = tid & 63;
    int lrow = lane & 15;
    int quad = lane >> 4;

    f32x4 acc[2][16];
#pragma unroll
    for (int a = 0; a < 2; a++)
#pragma unroll
        for (int b = 0; b < 16; b++) acc[a][b] = (f32x4)(0.f);

    // A staging: thread -> row tid>>1, 16 floats at col (tid&1)*16
    int arow = tid >> 1;
    int acol = (tid & 1) * 16;
    // B staging: thread -> one of 256 rows (4 matrices x 64), 32 floats
    int widx = tid >> 6;
    const float* Wsel = (widx == 0) ? Wk : (widx == 1) ? Wv : (widx == 2) ? Wq : Wa;
    const float* wrow = Wsel + (size_t)(tid & 63) * DIM;
    const float* xrow = x + (size_t)(m0 + arow) * DIM + acol;

    for (int k0 = 0; k0 < DIM; k0 += 32) {
        // load + convert to packed bf16 in registers (small live set across barrier)
        const float4* pa = (const float4*)(xrow + k0);
        float4 a0 = pa[0], a1 = pa[1], a2 = pa[2], a3 = pa[3];
        const float4* pb = (const float4*)(wrow + k0);
        float4 b0 = pb[0], b1 = pb[1], b2 = pb[2], b3 = pb[3];
        float4 b4 = pb[4], b5 = pb[5], b6 = pb[6], b7 = pb[7];

        unsigned apk[8], bpk[16];
        apk[0] = pk_bf(a0.x, a0.y); apk[1] = pk_bf(a0.z, a0.w);
        apk[2] = pk_bf(a1.x, a1.y); apk[3] = pk_bf(a1.z, a1.w);
        apk[4] = pk_bf(a2.x, a2.y); apk[5] = pk_bf(a2.z, a2.w);
        apk[6] = pk_bf(a3.x, a3.y); apk[7] = pk_bf(a3.z, a3.w);
        bpk[0]  = pk_bf(b0.x, b0.y); bpk[1]  = pk_bf(b0.z, b0.w);
        bpk[2]  = pk_bf(b1.x, b1.y); bpk[3]  = pk_bf(b1.z, b1.w);
        bpk[4]  = pk_bf(b2.x, b2.y); bpk[5]  = pk_bf(b2.z, b2.w);
        bpk[6]  = pk_bf(b3.x, b3.y); bpk[7]  = pk_bf(b3.z, b3.w);
        bpk[8]  = pk_bf(b4.x, b4.y); bpk[9]  = pk_bf(b4.z, b4.w);
        bpk[10] = pk_bf(b5.x, b5.y); bpk[11] = pk_bf(b5.z, b5.w);
        bpk[12] = pk_bf(b6.x, b6.y); bpk[13] = pk_bf(b6.z, b6.w);
        bpk[14] = pk_bf(b7.x, b7.y); bpk[15] = pk_bf(b7.z, b7.w);

        __syncthreads();  // protect previous iteration's frag reads

        ((uint4*)&lA[arow * LDA + acol])[0] = *(uint4*)&apk[0];
        ((uint4*)&lA[arow * LDA + acol + 8])[0] = *(uint4*)&apk[4];
        ((uint4*)&lB[tid * LDA])[0] = *(uint4*)&bpk[0];
        ((uint4*)&lB[tid * LDA + 8])[0] = *(uint4*)&bpk[4];
        ((uint4*)&lB[tid * LDA + 16])[0] = *(uint4*)&bpk[8];
        ((uint4*)&lB[tid * LDA + 24])[0] = *(uint4*)&bpk[12];

        __syncthreads();

        bf16x8 af[2];
#pragma unroll
        for (int rt = 0; rt < 2; rt++)
            af[rt] = *(const bf16x8*)&lA[(wave * 32 + rt * 16 + lrow) * LDA + quad * 8];
#pragma unroll
        for (int bt = 0; bt < 16; bt++) {
            bf16x8 bfr = *(const bf16x8*)&lB[(bt * 16 + lrow) * LDA + quad * 8];
            acc[0][bt] = __builtin_amdgcn_mfma_f32_16x16x32_bf16(af[0], bfr, acc[0][bt], 0, 0, 0);
            acc[1][bt] = __builtin_amdgcn_mfma_f32_16x16x32_bf16(af[1], bfr, acc[1][bt], 0, 0, 0);
        }
    }

    // epilogue: C/D layout col = lane&15, row = quad*4 + reg  [m89-verified]
#pragma unroll
    for (int rt = 0; rt < 2; rt++)
#pragma unroll
        for (int bt = 0; bt < 16; bt++) {
            int n = bt * 16 + lrow;
            float* outW = outBase + (size_t)(n >> 6) * M_TOTAL * NDIM + (n & 63);
#pragma unroll
            for (int reg = 0; reg < 4; reg++) {
                int m = m0 + wave * 32 + rt * 16 + quad * 4 + reg;
                outW[(size_t)m * NDIM] = acc[rt][bt][reg];
            }
        }
}

// ---------------- recurrence ----------------
// 16-lane DPP butterfly sum: all lanes of each 16-lane group end with the total.
template <int CTRL>
__device__ inline float dpp_add(float x) {
    int v = __builtin_amdgcn_update_dpp(0, __float_as_int(x), CTRL, 0xF, 0xF, true);
    return x + __int_as_float(v);
}
__device__ inline float red16(float x) {
    x = dpp_add<0xB1>(x);   // quad_perm xor1
    x = dpp_add<0x4E>(x);   // quad_perm xor2
    x = dpp_add<0x141>(x);  // row_half_mirror (xor4-equiv)
    x = dpp_add<0x140>(x);  // row_mirror      (xor8-equiv)
    return x;
}
__device__ inline float fast_sigmoid(float z) {
    return __builtin_amdgcn_rcpf(1.f + __expf(-z));
}

// grid (16 row-groups, 16 batches) x 64 threads; lane = r*16+c, row i=g*4+r,
// cols c*4..c*4+3. DPP rows (contiguous 16 lanes) == our c-groups.
__global__ __launch_bounds__(64, 1) void recur_kernel(
    const float* __restrict__ Kp, const float* __restrict__ Vp,
    const float* __restrict__ Qp, const float* __restrict__ Ap,
    const float* __restrict__ S0, const float* __restrict__ d_alpha,
    const float* __restrict__ b_alpha, float* __restrict__ out,
    float* __restrict__ Sout) {
    int b = blockIdx.y;
    int g = blockIdx.x;
    int lane = threadIdx.x;
    int r = lane >> 4;
    int c = lane & 15;
    int i = g * 4 + r;

    float4 s = *(const float4*)(S0 + ((size_t)b * NDIM + i) * NDIM + c * 4);
    float da = d_alpha[i];
    float ba = b_alpha[i];

    const int STRIDE = BATCH * NDIM;  // floats per timestep
    const float* pK = Kp + (size_t)b * NDIM + c * 4;
    const float* pQ = Qp + (size_t)b * NDIM + c * 4;
    const float* pV = Vp + (size_t)b * NDIM + i;
    const float* pA = Ap + (size_t)b * NDIM + i;

    float4 kb[PD], qb[PD];
    float vb[PD], ab[PD];
#pragma unroll
    for (int u = 0; u < PD; ++u) {
        kb[u] = *(const float4*)(pK + (size_t)u * STRIDE);
        qb[u] = *(const float4*)(pQ + (size_t)u * STRIDE);
        vb[u] = pV[(size_t)u * STRIDE];
        ab[u] = pA[(size_t)u * STRIDE];
    }

    for (int t0 = 0; t0 < T_STEPS; t0 += PD) {
#pragma unroll
        for (int u = 0; u < PD; ++u) {
            int t = t0 + u;
            float4 k = kb[u], q = qb[u];
            float v = vb[u], a = ab[u];

            // prefetch t+PD (clamped, branchless)
            int tn = t + PD;
            if (tn > T_STEPS - 1) tn = T_STEPS - 1;
            kb[u] = *(const float4*)(pK + (size_t)tn * STRIDE);
            qb[u] = *(const float4*)(pQ + (size_t)tn * STRIDE);
            vb[u] = pV[(size_t)tn * STRIDE];
            ab[u] = pA[(size_t)tn * STRIDE];

            float rk = k.x * s.x + k.y * s.y + k.z * s.z + k.w * s.w;
            float rq = q.x * s.x + q.y * s.y + q.z * s.z + q.w * s.w;
            float kq = k.x * q.x + k.y * q.y + k.z * q.z + k.w * q.w;
            rk = red16(rk);
            rq = red16(rq);
            kq = red16(kq);

            float alpha = fast_sigmoid(a + ba + da * rk);
            float u1 = (1.f - alpha) * v;

            s.x = fmaf(alpha, s.x, u1 * k.x);
            s.y = fmaf(alpha, s.y, u1 * k.y);
            s.z = fmaf(alpha, s.z, u1 * k.z);
            s.w = fmaf(alpha, s.w, u1 * k.w);

            // out = S_new . q = alpha*(S_old.q) + u1*(k.q)  (exact)
            float o = alpha * rq + u1 * kq;
            float ov = o * o * fast_sigmoid(o);
            if (c == 0) out[((size_t)t * BATCH + b) * NDIM + i] = ov;
        }
    }

    *(float4*)(Sout + ((size_t)b * NDIM + i) * NDIM + c * 4) = s;
}

extern "C" void kernel_launch(void* const* d_in, const int* in_sizes, int n_in,
                              void* d_out, int out_size, void* d_ws, size_t ws_size,
                              hipStream_t stream) {
    const float* x  = (const float*)d_in[0];
    const float* S0 = (const float*)d_in[1];
    const float* Wk = (const float*)d_in[2];
    const float* Wv = (const float*)d_in[3];
    const float* Wq = (const float*)d_in[4];
    const float* Wa = (const float*)d_in[5];
    const float* da = (const float*)d_in[6];
    const float* ba = (const float*)d_in[7];

    float* out = (float*)d_out;
    float* Sout = out + (size_t)T_STEPS * BATCH * NDIM;

    float* proj = (float*)d_ws;  // 4 * 32768 * 64 * 4B = 33.6 MB
    const size_t per = (size_t)M_TOTAL * NDIM;
    float* Kp = proj;
    float* Vp = proj + per;
    float* Qp = proj + 2 * per;
    float* Ap = proj + 3 * per;

    proj_kernel<<<dim3(M_TOTAL / 128), dim3(256), 0, stream>>>(x, Wk, Wv, Wq, Wa, proj);
    recur_kernel<<<dim3(16, BATCH), dim3(64), 0, stream>>>(Kp, Vp, Qp, Ap, S0, da, ba, out, Sout);
}

// Round 3
// 546.803 us; speedup vs baseline: 1.9630x; 1.2402x over previous
//
#include <hip/hip_runtime.h>
#include <hip/hip_bf16.h>

#define T_STEPS 2048
#define BATCH 16
#define DIM 1024
#define NDIM 64
#define M_TOTAL (T_STEPS * BATCH)  // 32768
#define STRIDE (BATCH * NDIM)      // floats per timestep = 1024
#define CH 32                      // recurrence chunk (timesteps per LDS buffer)

typedef __attribute__((ext_vector_type(8))) short bf16x8;
typedef __attribute__((ext_vector_type(4))) float f32x4;

__device__ inline unsigned pk_bf(float lo, float hi) {
    __hip_bfloat162 h = __float22bfloat162_rn(float2{lo, hi});
    return *(unsigned*)&h;  // v_cvt_pk_bf16_f32
}

// 16-lane DPP butterfly sum (within each contiguous 16-lane row)
template <int CTRL>
__device__ inline float dpp_add(float x) {
    int v = __builtin_amdgcn_update_dpp(0, __float_as_int(x), CTRL, 0xF, 0xF, true);
    return x + __int_as_float(v);
}
__device__ inline float red16(float x) {
    x = dpp_add<0xB1>(x);   // quad_perm xor1
    x = dpp_add<0x4E>(x);   // quad_perm xor2
    x = dpp_add<0x141>(x);  // row_half_mirror
    x = dpp_add<0x140>(x);  // row_mirror
    return x;
}
__device__ inline float fast_sigmoid(float z) {
    return __builtin_amdgcn_rcpf(1.f + __expf(-z));
}

#define AS1 __attribute__((address_space(1)))
#define AS3 __attribute__((address_space(3)))
__device__ inline void gl_lds16(const float* g, float* l) {
    __builtin_amdgcn_global_load_lds((const AS1 unsigned*)g, (AS3 unsigned*)l, 16, 0, 0);
}
__device__ inline void gl_lds4(const float* g, float* l) {
    __builtin_amdgcn_global_load_lds((const AS1 unsigned*)g, (AS3 unsigned*)l, 4, 0, 0);
}
#define WAIT_VM0 do { __builtin_amdgcn_s_waitcnt(0x0F70); asm volatile("" ::: "memory"); } while (0)

// ---------------- fused projection + kq precompute ----------------
// 64 M-rows per block (512 blocks = 2/CU), N=256 (4 matrices x 64).
__global__ __launch_bounds__(256, 2) void proj_kernel(
    const float* __restrict__ x,
    const float* __restrict__ Wk, const float* __restrict__ Wv,
    const float* __restrict__ Wq, const float* __restrict__ Wa,
    const float* __restrict__ ba,
    float* __restrict__ outBase, float* __restrict__ kqOut) {
    const int LDA = 40;
    __shared__ unsigned short lA[64 * 40];   // 5 KB
    __shared__ unsigned short lB[256 * 40];  // 20 KB

    int m0 = blockIdx.x * 64;
    int tid = threadIdx.x;
    int wave = tid >> 6;
    int lane = tid & 63;
    int lrow = lane & 15;
    int quad = lane >> 4;

    f32x4 acc[16];
#pragma unroll
    for (int b = 0; b < 16; b++) acc[b] = (f32x4)(0.f);

    int arow = tid >> 2;
    int acol = (tid & 3) * 8;
    int widx = tid >> 6;
    const float* Wsel = (widx == 0) ? Wk : (widx == 1) ? Wv : (widx == 2) ? Wq : Wa;
    const float* wrow = Wsel + (size_t)(tid & 63) * DIM;
    const float* xrow = x + (size_t)(m0 + arow) * DIM + acol;

    // preload + convert iter 0
    float4 a0 = ((const float4*)xrow)[0], a1 = ((const float4*)xrow)[1];
    float4 bb[8];
#pragma unroll
    for (int jj = 0; jj < 8; jj++) bb[jj] = ((const float4*)wrow)[jj];
    unsigned apk[4], bpk[16];
    apk[0] = pk_bf(a0.x, a0.y); apk[1] = pk_bf(a0.z, a0.w);
    apk[2] = pk_bf(a1.x, a1.y); apk[3] = pk_bf(a1.z, a1.w);
#pragma unroll
    for (int jj = 0; jj < 8; jj++) {
        bpk[2 * jj] = pk_bf(bb[jj].x, bb[jj].y);
        bpk[2 * jj + 1] = pk_bf(bb[jj].z, bb[jj].w);
    }

    for (int k0 = 0; k0 < DIM; k0 += 32) {
        __syncthreads();  // waves done reading LDS from previous iter
        *(uint4*)&lA[arow * LDA + acol] = *(uint4*)&apk[0];
        *(uint4*)&lB[tid * LDA + 0]  = *(uint4*)&bpk[0];
        *(uint4*)&lB[tid * LDA + 8]  = *(uint4*)&bpk[4];
        *(uint4*)&lB[tid * LDA + 16] = *(uint4*)&bpk[8];
        *(uint4*)&lB[tid * LDA + 24] = *(uint4*)&bpk[12];
        __syncthreads();

        // issue next-iter global loads (latency hidden behind MFMA below)
        bool more = (k0 + 32) < DIM;
        float4 na0, na1, nb[8];
        if (more) {
            const float4* pa = (const float4*)(xrow + k0 + 32);
            na0 = pa[0]; na1 = pa[1];
            const float4* pb = (const float4*)(wrow + k0 + 32);
#pragma unroll
            for (int jj = 0; jj < 8; jj++) nb[jj] = pb[jj];
        }

        bf16x8 af = *(const bf16x8*)&lA[(wave * 16 + lrow) * LDA + quad * 8];
#pragma unroll
        for (int bt = 0; bt < 16; bt++) {
            bf16x8 bfr = *(const bf16x8*)&lB[(bt * 16 + lrow) * LDA + quad * 8];
            acc[bt] = __builtin_amdgcn_mfma_f32_16x16x32_bf16(af, bfr, acc[bt], 0, 0, 0);
        }

        if (more) {
            apk[0] = pk_bf(na0.x, na0.y); apk[1] = pk_bf(na0.z, na0.w);
            apk[2] = pk_bf(na1.x, na1.y); apk[3] = pk_bf(na1.z, na1.w);
#pragma unroll
            for (int jj = 0; jj < 8; jj++) {
                bpk[2 * jj] = pk_bf(nb[jj].x, nb[jj].y);
                bpk[2 * jj + 1] = pk_bf(nb[jj].z, nb[jj].w);
            }
        }
    }

    // ---- epilogue ----
    // fold +b_alpha into the alpha projection (bt 12..15)
#pragma unroll
    for (int bt = 12; bt < 16; bt++) {
        float bav = ba[(bt - 12) * 16 + lrow];
#pragma unroll
        for (int reg = 0; reg < 4; reg++) acc[bt][reg] += bav;
    }
    // stores: C/D layout col = lane&15, row = quad*4 + reg  [m89-verified]
    const size_t per = (size_t)M_TOTAL * NDIM;
#pragma unroll
    for (int bt = 0; bt < 16; bt++) {
        int n = bt * 16 + lrow;
        float* outW = outBase + (size_t)(n >> 6) * per + (n & 63);
#pragma unroll
        for (int reg = 0; reg < 4; reg++) {
            int m = m0 + wave * 16 + quad * 4 + reg;
            outW[(size_t)m * NDIM] = acc[bt][reg];
        }
    }
    // kq[m] = K[m,:] . Q[m,:]  (K = bt 0..3, Q = bt 8..11); reduce across 16 lanes
#pragma unroll
    for (int reg = 0; reg < 4; reg++) {
        float p = acc[0][reg] * acc[8][reg] + acc[1][reg] * acc[9][reg] +
                  acc[2][reg] * acc[10][reg] + acc[3][reg] * acc[11][reg];
        p = red16(p);
        if (lrow == 0) kqOut[m0 + wave * 16 + quad * 4 + reg] = p;
    }
}

// ---------------- recurrence: single-wave blocks, LDS double-buffered ----------------
// grid (16 row-groups, 16 batches) x 64 threads; lane = r*16+c; row i=g*4+r, cols c*4..+3
__global__ __launch_bounds__(64, 1) void recur_kernel(
    const float* __restrict__ Kp, const float* __restrict__ Vp,
    const float* __restrict__ Qp, const float* __restrict__ Ap,
    const float* __restrict__ KQp, const float* __restrict__ S0,
    const float* __restrict__ d_alpha, float* __restrict__ out,
    float* __restrict__ Sout) {
    __shared__ float Kl[2][CH][64];   // 16 KB
    __shared__ float Ql[2][CH][64];   // 16 KB
    __shared__ float VAl[2][CH][8];   // 2 KB  ([t][0..3]=v rows, [t][4..7]=a rows)
    __shared__ float KQl[2][64];      // 0.5 KB

    int b = blockIdx.y;
    int g = blockIdx.x;
    int lane = threadIdx.x;
    int r = lane >> 4;
    int c = lane & 15;
    int i = g * 4 + r;
    int c4 = c * 4;

    float4 s = *(const float4*)(S0 + ((size_t)b * NDIM + i) * NDIM + c4);
    float da = d_alpha[i];

    // staging address bases (lane roles for staging differ from compute roles)
    const float* Kbase = Kp + (size_t)b * NDIM + (size_t)(lane >> 4) * STRIDE + (lane & 15) * 4;
    const float* Qbase = Qp + (size_t)b * NDIM + (size_t)(lane >> 4) * STRIDE + (lane & 15) * 4;
    const float* VAbase = ((lane & 1) ? Ap : Vp) + (size_t)b * NDIM + g * 4 + (size_t)(lane >> 1) * STRIDE;
    const float* KQbase = KQp + b + (size_t)(lane & 31) * BATCH;

    auto load_chunk = [&](int t0, int buf) {
#pragma unroll
        for (int j = 0; j < 8; ++j) {
            gl_lds16(Kbase + (size_t)(t0 + j * 4) * STRIDE, &Kl[buf][j * 4][0]);
            gl_lds16(Qbase + (size_t)(t0 + j * 4) * STRIDE, &Ql[buf][j * 4][0]);
        }
        gl_lds16(VAbase + (size_t)t0 * STRIDE, &VAl[buf][0][0]);
        gl_lds4(KQbase + (size_t)t0 * BATCH, &KQl[buf][0]);
    };

    load_chunk(0, 0);
    WAIT_VM0;

    float* ob = out + (size_t)b * NDIM + i;  // + t*STRIDE per step

    for (int j = 0; j < T_STEPS / CH; ++j) {
        int cb = j & 1;
        if (j < T_STEPS / CH - 1) load_chunk((j + 1) * CH, cb ^ 1);

        const float* Kb = &Kl[cb][0][0];
        const float* Qb = &Ql[cb][0][0];
        const float* Vb = &VAl[cb][0][0];
        const float* Qk = &KQl[cb][0];

        // LDS->reg software pipeline, depth 2
        float4 kr[2], qr[2];
        float vr[2], ar[2], kqr[2];
#pragma unroll
        for (int u = 0; u < 2; ++u) {
            kr[u] = *(const float4*)(Kb + u * 64 + c4);
            qr[u] = *(const float4*)(Qb + u * 64 + c4);
            vr[u] = Vb[u * 8 + r];
            ar[u] = Vb[u * 8 + 4 + r];
            kqr[u] = Qk[u];
        }

#pragma unroll
        for (int tl = 0; tl < CH; ++tl) {
            int sl = tl & 1;
            float4 k = kr[sl], q = qr[sl];
            float v = vr[sl], aa = ar[sl], kq = kqr[sl];
            if (tl < CH - 2) {
                kr[sl] = *(const float4*)(Kb + (tl + 2) * 64 + c4);
                qr[sl] = *(const float4*)(Qb + (tl + 2) * 64 + c4);
                vr[sl] = Vb[(tl + 2) * 8 + r];
                ar[sl] = Vb[(tl + 2) * 8 + 4 + r];
                kqr[sl] = Qk[tl + 2];
            }

            float rk = fmaf(k.y, s.y, k.x * s.x) + fmaf(k.w, s.w, k.z * s.z);
            float rq = fmaf(q.y, s.y, q.x * s.x) + fmaf(q.w, s.w, q.z * s.z);
            rk = red16(rk);
            rq = red16(rq);

            float z = fmaf(da, rk, aa);           // aa already includes b_alpha
            float alpha = fast_sigmoid(z);
            float u1 = (1.f - alpha) * v;

            s.x = fmaf(alpha, s.x, u1 * k.x);
            s.y = fmaf(alpha, s.y, u1 * k.y);
            s.z = fmaf(alpha, s.z, u1 * k.z);
            s.w = fmaf(alpha, s.w, u1 * k.w);

            float o = fmaf(alpha, rq, u1 * kq);   // S_new.q = alpha*(S_old.q) + u1*(k.q)
            float ov = o * o * fast_sigmoid(o);
            if (c == 0) ob[(size_t)(j * CH + tl) * STRIDE] = ov;
        }
        WAIT_VM0;  // next chunk staged long ago; drains only trailing stores
    }

    *(float4*)(Sout + ((size_t)b * NDIM + i) * NDIM + c4) = s;
}

extern "C" void kernel_launch(void* const* d_in, const int* in_sizes, int n_in,
                              void* d_out, int out_size, void* d_ws, size_t ws_size,
                              hipStream_t stream) {
    const float* x  = (const float*)d_in[0];
    const float* S0 = (const float*)d_in[1];
    const float* Wk = (const float*)d_in[2];
    const float* Wv = (const float*)d_in[3];
    const float* Wq = (const float*)d_in[4];
    const float* Wa = (const float*)d_in[5];
    const float* da = (const float*)d_in[6];
    const float* ba = (const float*)d_in[7];

    float* out = (float*)d_out;
    float* Sout = out + (size_t)T_STEPS * BATCH * NDIM;

    float* proj = (float*)d_ws;  // 4*32768*64*4B = 33.55 MB (+128 KB kq)
    const size_t per = (size_t)M_TOTAL * NDIM;
    float* Kp = proj;
    float* Vp = proj + per;
    float* Qp = proj + 2 * per;
    float* Ap = proj + 3 * per;
    float* kq = proj + 4 * per;

    proj_kernel<<<dim3(M_TOTAL / 64), dim3(256), 0, stream>>>(x, Wk, Wv, Wq, Wa, ba, proj, kq);
    recur_kernel<<<dim3(16, BATCH), dim3(64), 0, stream>>>(Kp, Vp, Qp, Ap, kq, S0, da, out, Sout);
}